// Round 10
// baseline (213.500 us; speedup 1.0000x reference)
//
#include <hip/hip_runtime.h>
#include <math.h>

// ---------------------------------------------------------------------------
// PermutedNetwork, R10.
// R9 analysis: deform_patch phase2 issued 24 ds_read_b128 per 128 FMA per k
// (LDS pipe ~= VALU pipe -> 50% stall) + 18 k-loop barriers for weight staging.
// Fix: wave-per-output-group phase2. og = tid>>6 (readfirstlane-uniform) ->
// weight reads are wave-uniform scalar loads from global wT (SGPR operands,
// scalar pipe), zero barriers in k loop, 1 patch ds_read per 32-64 FMA.
// deform1 / pools / conv3x3_off / poolfc / wtrans unchanged (proven R6-R9).
// ---------------------------------------------------------------------------

// ---- Weight transpose: w[o][c][k] -> wT[k][c][o] (run once, tiny).
template <int CIN, int COUT>
__global__ void wtrans(const float* __restrict__ w, float* __restrict__ wT) {
  int t = blockIdx.x * 256 + threadIdx.x;
  if (t >= 9 * CIN * COUT) return;
  int k = t / (CIN * COUT);
  int r = t % (CIN * COUT);
  int c = r / COUT;
  int o = r % COUT;
  wT[t] = w[(o * CIN + c) * 9 + k];
}

// ---- Layer 1: fused offset-conv + deform + relu, CIN=1. 2 pixels/thread.
__global__ void deform1_fused(const float* __restrict__ x,    // [64,96,96]
                              const float* __restrict__ woff, // [18,1,3,3]
                              const float* __restrict__ boff, // [18]
                              const float* __restrict__ w1,   // [16,1,3,3]
                              const float* __restrict__ b1,   // [16]
                              float* __restrict__ out) {      // [64,16,96,96]
  const int H = 96, W = 96, HW = H * W;
  __shared__ float wos[9 * 18];
  __shared__ __align__(16) float ws1[9 * 16];
  for (int t = threadIdx.x; t < 9 * 18; t += 256) { int k = t / 18, tc = t % 18; wos[t] = woff[tc * 9 + k]; }
  for (int t = threadIdx.x; t < 9 * 16; t += 256) { int k = t / 16, o = t % 16; ws1[t] = w1[o * 9 + k]; }
  __syncthreads();

  int gid = blockIdx.x * 256 + threadIdx.x;
  int p2 = gid % (HW / 2);
  int b  = gid / (HW / 2);
  int xi0 = (2 * p2) % W, yi = (2 * p2) / W;
  const float* xb = x + (size_t)b * HW;

  float v[3][4];
#pragma unroll
  for (int r = 0; r < 3; ++r) {
    int yy = yi + r - 1;
    float my = (yy >= 0 && yy < H) ? 1.f : 0.f;
    int cy = min(max(yy, 0), H - 1);
#pragma unroll
    for (int c = 0; c < 4; ++c) {
      int xx = xi0 + c - 1;
      float mx = (xx >= 0 && xx < W) ? 1.f : 0.f;
      int cx = min(max(xx, 0), W - 1);
      v[r][c] = xb[cy * W + cx] * (my * mx);
    }
  }

  float off0[18], off1[18];
#pragma unroll
  for (int tc = 0; tc < 18; ++tc) { float bb = boff[tc]; off0[tc] = bb; off1[tc] = bb; }
#pragma unroll
  for (int r = 0; r < 3; ++r)
#pragma unroll
    for (int c = 0; c < 3; ++c) {
      float t0 = v[r][c], t1 = v[r][c + 1];
      const float2* wv = (const float2*)&wos[(r * 3 + c) * 18];
#pragma unroll
      for (int tt = 0; tt < 9; ++tt) {
        float2 ww = wv[tt];
        off0[2 * tt]     = fmaf(ww.x, t0, off0[2 * tt]);
        off0[2 * tt + 1] = fmaf(ww.y, t0, off0[2 * tt + 1]);
        off1[2 * tt]     = fmaf(ww.x, t1, off1[2 * tt]);
        off1[2 * tt + 1] = fmaf(ww.y, t1, off1[2 * tt + 1]);
      }
    }

  float acc0[16], acc1[16];
#pragma unroll
  for (int o = 0; o < 16; ++o) { float bb = b1[o]; acc0[o] = bb; acc1[o] = bb; }

#pragma unroll
  for (int k = 0; k < 9; ++k) {
    int dky = k / 3 - 1, dkx = k % 3 - 1;
    float val0, val1;
    {
      float py = (float)(yi + dky) + off0[2 * k];
      float px = (float)(xi0 + dkx) + off0[2 * k + 1];
      float y0f = floorf(py), x0f = floorf(px);
      float fy = py - y0f, fx = px - x0f;
      int y0 = (int)y0f, x0 = (int)x0f, y1 = y0 + 1, x1 = x0 + 1;
      float vy0 = (y0 >= 0 && y0 < H) ? 1.f : 0.f;
      float vy1 = (y1 >= 0 && y1 < H) ? 1.f : 0.f;
      float vx0 = (x0 >= 0 && x0 < W) ? 1.f : 0.f;
      float vx1 = (x1 >= 0 && x1 < W) ? 1.f : 0.f;
      float w00 = (1.f - fy) * (1.f - fx) * vy0 * vx0;
      float w01 = (1.f - fy) * fx * vy0 * vx1;
      float w10 = fy * (1.f - fx) * vy1 * vx0;
      float w11 = fy * fx * vy1 * vx1;
      int cy0 = min(max(y0, 0), H - 1), cy1 = min(max(y1, 0), H - 1);
      int cx0 = min(max(x0, 0), W - 1), cx1 = min(max(x1, 0), W - 1);
      float a = xb[cy0 * W + cx0], bb = xb[cy0 * W + cx1];
      float c = xb[cy1 * W + cx0], d = xb[cy1 * W + cx1];
      val0 = w00 * a + w01 * bb + w10 * c + w11 * d;
    }
    {
      float py = (float)(yi + dky) + off1[2 * k];
      float px = (float)(xi0 + 1 + dkx) + off1[2 * k + 1];
      float y0f = floorf(py), x0f = floorf(px);
      float fy = py - y0f, fx = px - x0f;
      int y0 = (int)y0f, x0 = (int)x0f, y1 = y0 + 1, x1 = x0 + 1;
      float vy0 = (y0 >= 0 && y0 < H) ? 1.f : 0.f;
      float vy1 = (y1 >= 0 && y1 < H) ? 1.f : 0.f;
      float vx0 = (x0 >= 0 && x0 < W) ? 1.f : 0.f;
      float vx1 = (x1 >= 0 && x1 < W) ? 1.f : 0.f;
      float w00 = (1.f - fy) * (1.f - fx) * vy0 * vx0;
      float w01 = (1.f - fy) * fx * vy0 * vx1;
      float w10 = fy * (1.f - fx) * vy1 * vx0;
      float w11 = fy * fx * vy1 * vx1;
      int cy0 = min(max(y0, 0), H - 1), cy1 = min(max(y1, 0), H - 1);
      int cx0 = min(max(x0, 0), W - 1), cx1 = min(max(x1, 0), W - 1);
      float a = xb[cy0 * W + cx0], bb = xb[cy0 * W + cx1];
      float c = xb[cy1 * W + cx0], d = xb[cy1 * W + cx1];
      val1 = w00 * a + w01 * bb + w10 * c + w11 * d;
    }
    const float4* wv = (const float4*)&ws1[k * 16];
#pragma unroll
    for (int q = 0; q < 4; ++q) {
      float4 w4 = wv[q];
      acc0[4 * q + 0] = fmaf(w4.x, val0, acc0[4 * q + 0]);
      acc0[4 * q + 1] = fmaf(w4.y, val0, acc0[4 * q + 1]);
      acc0[4 * q + 2] = fmaf(w4.z, val0, acc0[4 * q + 2]);
      acc0[4 * q + 3] = fmaf(w4.w, val0, acc0[4 * q + 3]);
      acc1[4 * q + 0] = fmaf(w4.x, val1, acc1[4 * q + 0]);
      acc1[4 * q + 1] = fmaf(w4.y, val1, acc1[4 * q + 1]);
      acc1[4 * q + 2] = fmaf(w4.z, val1, acc1[4 * q + 2]);
      acc1[4 * q + 3] = fmaf(w4.w, val1, acc1[4 * q + 3]);
    }
  }

  float* op = out + (size_t)b * 16 * HW + (size_t)yi * W + xi0;
#pragma unroll
  for (int o = 0; o < 16; ++o) {
    float2 r = make_float2(fmaxf(acc0[o], 0.f), fmaxf(acc1[o], 0.f));
    *(float2*)(op + (size_t)o * HW) = r;
  }
}

// ---- 2x2 maxpool, NCHW in -> NHWC out.
template <int C, int HI>
__global__ void pool_nchw_to_nhwc(const float* __restrict__ in,  // [B,C,HI,HI]
                                  float* __restrict__ out) {     // [B,HO,HO,C]
  const int HO = HI / 2, C4 = C / 4;
  int gid = blockIdx.x * blockDim.x + threadIdx.x;
  if (gid >= 64 * HO * HO * C4) return;
  int c4 = gid % C4;
  int t = gid / C4;
  int x = t % HO; t /= HO;
  int y = t % HO;
  int b = t / HO;
  float4 r;
  float* rp = &r.x;
#pragma unroll
  for (int cc = 0; cc < 4; ++cc) {
    int c = c4 * 4 + cc;
    const float* p = in + ((size_t)(b * C + c) * HI + 2 * y) * HI + 2 * x;
    rp[cc] = fmaxf(fmaxf(p[0], p[1]), fmaxf(p[HI], p[HI + 1]));
  }
  *(float4*)(out + (((size_t)b * HO + y) * HO + x) * C + c4 * 4) = r;
}

// ---- 3x3 conv for offsets: NHWC in, PADDED NHWC out [B,H,W,20].
template <int CIN, int COUT, int NSPLIT>
__global__ __launch_bounds__(256, 4)
void conv3x3_off(const float* __restrict__ in,  // [B,H,W,CIN]
                 const float* __restrict__ w,   // [COUT,CIN,3,3]
                 const float* __restrict__ bias,
                 float* __restrict__ out,       // [B,H,W,20]
                 int B, int H, int W) {
  constexpr int OC = COUT / NSPLIT;
  __shared__ float ws[9 * CIN * OC];
  int obase = blockIdx.y * OC;
  for (int t = threadIdx.x; t < 9 * CIN * OC; t += 256) {
    int k = t / (CIN * OC); int r = t % (CIN * OC);
    int c = r / OC; int o = r % OC;
    ws[t] = w[((obase + o) * CIN + c) * 9 + k];
  }
  __syncthreads();

  int gid = blockIdx.x * 256 + threadIdx.x;
  if (gid >= B * H * W) return;
  int x = gid % W; int t0 = gid / W; int y = t0 % H; int b = t0 / H;
  int HW = H * W;
  const float* inb = in + (size_t)b * HW * CIN;

  float acc[OC];
#pragma unroll
  for (int o = 0; o < OC; ++o) acc[o] = bias[obase + o];

#pragma unroll
  for (int ky = 0; ky < 3; ++ky) {
    int yy = y + ky - 1;
    if (yy < 0 || yy >= H) continue;
#pragma unroll
    for (int kx = 0; kx < 3; ++kx) {
      int xx = x + kx - 1;
      if (xx < 0 || xx >= W) continue;
      const float4* p4 = (const float4*)(inb + ((size_t)yy * W + xx) * CIN);
      int k = ky * 3 + kx;
#pragma unroll
      for (int c4 = 0; c4 < CIN / 4; ++c4) {
        float4 p = p4[c4];
        const float* pv = &p.x;
#pragma unroll
        for (int cc = 0; cc < 4; ++cc) {
          const float* wrow = &ws[(k * CIN + 4 * c4 + cc) * OC];
#pragma unroll
          for (int o = 0; o < OC; ++o) acc[o] = fmaf(wrow[o], pv[cc], acc[o]);
        }
      }
    }
  }

  float* op = out + (size_t)gid * 20 + obase;
#pragma unroll
  for (int o = 0; o < OC; ++o) op[o] = acc[o];
}

// ---- Wave-per-og patch-LDS deformable conv + ReLU.
// Phase1: 256 thr build interpolated patches into LDS (PX=64 pixels).
// Phase2: wave = output-channel group (uniform -> weights via scalar loads
// from global wT), lane = pixel. No barriers in the k loop.
template <int CIN, int COUT, int HW_>
__global__ void deform_sgpr(const float* __restrict__ in,     // [B,H,W,CIN]
                            const float* __restrict__ off_in, // [B*HW,20]
                            const float* __restrict__ wT,     // [9][CIN][COUT]
                            const float* __restrict__ bias,
                            float* __restrict__ out) {        // [B,COUT,H,W]
  constexpr int H = HW_, W = HW_, HW = H * W;
  constexpr int PX = 64;
  constexpr int QT = CIN / 4;        // 4 (L2) / 8 (L3)
  constexpr int QPT = QT / 4;        // quads per phase1-thread: 1 / 2
  constexpr int PSTR = 9 * CIN + 4;  // 148 / 292 (stride/4 odd -> even banks)
  constexpr int OPG = COUT / 4;      // 8 / 16 outputs per wave-lane

  __shared__ __align__(16) float offs[PX * 20];
  __shared__ __align__(16) float patch[PX * PSTR];

  const int pixbase = blockIdx.x * PX;
  const int b = pixbase / HW;
  const int p0 = pixbase - b * HW;
  const float* inb = in + (size_t)b * HW * CIN;

  {
    const float4* src = (const float4*)(off_in + (size_t)pixbase * 20);
    for (int t = threadIdx.x; t < PX * 20 / 4; t += 256)
      ((float4*)offs)[t] = src[t];
  }
  __syncthreads();

  // ---- phase 1: build interpolated patches
  {
    int px = threadIdx.x & 63;
    int qp = threadIdx.x >> 6;    // 0..3
    int pib = p0 + px;
    int yi = pib / W, xi = pib % W;
#pragma unroll
    for (int k = 0; k < 9; ++k) {
      float py  = (float)(yi + k / 3 - 1) + offs[px * 20 + 2 * k];
      float pxx = (float)(xi + k % 3 - 1) + offs[px * 20 + 2 * k + 1];
      float y0f = floorf(py), x0f = floorf(pxx);
      float fy = py - y0f, fx = pxx - x0f;
      int y0 = (int)y0f, x0 = (int)x0f, y1 = y0 + 1, x1 = x0 + 1;
      float vy0 = (y0 >= 0 && y0 < H) ? 1.f : 0.f;
      float vy1 = (y1 >= 0 && y1 < H) ? 1.f : 0.f;
      float vx0 = (x0 >= 0 && x0 < W) ? 1.f : 0.f;
      float vx1 = (x1 >= 0 && x1 < W) ? 1.f : 0.f;
      float w00 = (1.f - fy) * (1.f - fx) * vy0 * vx0;
      float w01 = (1.f - fy) * fx * vy0 * vx1;
      float w10 = fy * (1.f - fx) * vy1 * vx0;
      float w11 = fy * fx * vy1 * vx1;
      int cy0 = min(max(y0, 0), H - 1), cy1 = min(max(y1, 0), H - 1);
      int cx0 = min(max(x0, 0), W - 1), cx1 = min(max(x1, 0), W - 1);
      const float* r00 = inb + ((size_t)cy0 * W + cx0) * CIN;
      const float* r01 = inb + ((size_t)cy0 * W + cx1) * CIN;
      const float* r10 = inb + ((size_t)cy1 * W + cx0) * CIN;
      const float* r11 = inb + ((size_t)cy1 * W + cx1) * CIN;
#pragma unroll
      for (int j = 0; j < QPT; ++j) {
        int q = qp + j * 4;
        float4 A  = *(const float4*)(r00 + 4 * q);
        float4 Bv = *(const float4*)(r01 + 4 * q);
        float4 Cv = *(const float4*)(r10 + 4 * q);
        float4 Dv = *(const float4*)(r11 + 4 * q);
        float4 val;
        val.x = w00 * A.x + w01 * Bv.x + w10 * Cv.x + w11 * Dv.x;
        val.y = w00 * A.y + w01 * Bv.y + w10 * Cv.y + w11 * Dv.y;
        val.z = w00 * A.z + w01 * Bv.z + w10 * Cv.z + w11 * Dv.z;
        val.w = w00 * A.w + w01 * Bv.w + w10 * Cv.w + w11 * Dv.w;
        *(float4*)&patch[px * PSTR + k * CIN + 4 * q] = val;
      }
    }
  }
  __syncthreads();

  // ---- phase 2: wave = og, lane = px; weights via wave-uniform scalar loads
  int px = threadIdx.x & 63;
  int og = __builtin_amdgcn_readfirstlane(threadIdx.x >> 6);
  int obase = og * OPG;

  float acc[OPG];
#pragma unroll
  for (int o = 0; o < OPG; ++o) acc[o] = bias[obase + o];

  const float* patp = &patch[px * PSTR];
  for (int k = 0; k < 9; ++k) {
#pragma unroll
    for (int c4 = 0; c4 < QT; ++c4) {
      float4 p = *(const float4*)&patp[k * CIN + 4 * c4];
      const float* pv = &p.x;
      const float* wb = wT + ((size_t)(k * CIN + 4 * c4)) * COUT + obase;
#pragma unroll
      for (int cc = 0; cc < 4; ++cc)
#pragma unroll
        for (int o = 0; o < OPG; ++o)
          acc[o] = fmaf(wb[cc * COUT + o], pv[cc], acc[o]);
    }
  }

  float* ob = out + ((size_t)b * COUT + obase) * HW + p0 + px;
#pragma unroll
  for (int o = 0; o < OPG; ++o)
    ob[(size_t)o * HW] = fmaxf(acc[o], 0.f);
}

// ---- Adaptive avg pool 24->3 (8x8 bins) + fc(576->10), NCHW input.
__global__ void poolfc_kernel(const float* __restrict__ h,   // [B,64,24,24]
                              const float* __restrict__ wfc, // [10,576]
                              const float* __restrict__ bfc, // [10]
                              float* __restrict__ out) {     // [B,10]
  __shared__ float feat[576];
  int b = blockIdx.x;
  int f = threadIdx.x; // 576 threads
  int c = f / 9, ij = f % 9, i = ij / 3, j = ij % 3;
  const float* p = h + ((size_t)(b * 64 + c) * 24 + i * 8) * 24 + j * 8;
  float s = 0.f;
#pragma unroll
  for (int r = 0; r < 8; ++r)
#pragma unroll
    for (int q = 0; q < 8; ++q)
      s += p[r * 24 + q];
  feat[f] = s * (1.f / 64.f);
  __syncthreads();
  if (f < 10) {
    float acc = bfc[f];
    const float* wp = wfc + f * 576;
    for (int t = 0; t < 576; ++t) acc = fmaf(wp[t], feat[t], acc);
    out[b * 10 + f] = acc;
  }
}

extern "C" void kernel_launch(void* const* d_in, const int* in_sizes, int n_in,
                              void* d_out, int out_size, void* d_ws, size_t ws_size,
                              hipStream_t stream) {
  const float* x      = (const float*)d_in[0];
  const float* w_off1 = (const float*)d_in[1];
  const float* b_off1 = (const float*)d_in[2];
  const float* w1     = (const float*)d_in[3];
  const float* b1     = (const float*)d_in[4];
  const float* w_off2 = (const float*)d_in[5];
  const float* b_off2 = (const float*)d_in[6];
  const float* w2     = (const float*)d_in[7];
  const float* b2     = (const float*)d_in[8];
  const float* w_off3 = (const float*)d_in[9];
  const float* b_off3 = (const float*)d_in[10];
  const float* w3     = (const float*)d_in[11];
  const float* b3     = (const float*)d_in[12];
  const float* w_fc   = (const float*)d_in[13];
  const float* b_fc   = (const float*)d_in[14];
  float* out = (float*)d_out;

  char* ws = (char*)d_ws;
  float* A   = (float*)(ws);
  float* Cp  = (float*)(ws + 18874368);
  float* Bp  = (float*)(ws + 37748736);
  float* wT2 = (float*)(ws + 47185920);
  float* wT3 = (float*)(ws + 47185920 + 9 * 16 * 32 * 4);

  const int thr = 256;

  // Weight transposes (independent, run first)
  wtrans<16, 32><<<(9 * 16 * 32 + 255) / 256, thr, 0, stream>>>(w2, wT2);
  wtrans<32, 64><<<(9 * 32 * 64 + 255) / 256, thr, 0, stream>>>(w3, wT3);

  // Layer 1: fused offset+deform+relu -> A [64,16,96,96] NCHW (2 px/thread)
  deform1_fused<<<64 * 96 * 96 / 2 / thr, thr, 0, stream>>>(x, w_off1, b_off1, w1, b1, A);
  // pool -> Bp [64,48,48,16] NHWC
  {
    int total = 64 * 48 * 48 * 4;
    pool_nchw_to_nhwc<16, 96><<<(total + thr - 1) / thr, thr, 0, stream>>>(A, Bp);
  }

  // Layer 2: offset conv -> Cp [64,48,48,20] padded NHWC
  conv3x3_off<16, 18, 1><<<dim3(576, 1), thr, 0, stream>>>(Bp, w_off2, b_off2, Cp, 64, 48, 48);
  // deform + relu -> A [64,32,48,48] NCHW  (2304 blocks, 42KB LDS)
  deform_sgpr<16, 32, 48><<<64 * 48 * 48 / 64, thr, 0, stream>>>(Bp, Cp, wT2, b2, A);
  // pool -> Bp [64,24,24,32] NHWC
  {
    int total = 64 * 24 * 24 * 8;
    pool_nchw_to_nhwc<32, 48><<<(total + thr - 1) / thr, thr, 0, stream>>>(A, Bp);
  }

  // Layer 3: offset conv -> Cp [64,24,24,20] padded NHWC
  conv3x3_off<32, 18, 3><<<dim3(144, 3), thr, 0, stream>>>(Bp, w_off3, b_off3, Cp, 64, 24, 24);
  // deform + relu -> A [64,64,24,24] NCHW  (576 blocks, 78KB LDS)
  deform_sgpr<32, 64, 24><<<64 * 24 * 24 / 64, thr, 0, stream>>>(Bp, Cp, wT3, b3, A);

  // avgpool(3x3) + fc -> out [64,10]
  poolfc_kernel<<<64, 576, 0, stream>>>(A, w_fc, b_fc, out);
}